// Round 1
// baseline (421.643 us; speedup 1.0000x reference)
//
#include <hip/hip_runtime.h>

// AdaptiveSparseUpdateRule: fused sobel-feats + 48->128->128->16 MLP + alive/fire mask.
// bf16 MFMA (16x16x32) for the MLP, fp32 for sobel + mask path.
//
// Layout: grid = 256 blocks = (batch 16) x (16-row strips 16); block = 512 thr (8 waves).
// Each block loops h (16 rows) x wt (4 tiles of 64 pixels). Weights staged once/block.

#define TPB 512

using bf16x8 = __attribute__((ext_vector_type(8))) __bf16;
using s16x8  = __attribute__((ext_vector_type(8))) short;
using f32x4  = __attribute__((ext_vector_type(4))) float;

__device__ __forceinline__ unsigned short f2bf(float f) {
    unsigned int u = __float_as_uint(f);
    u += 0x7fffu + ((u >> 16) & 1u);   // round-to-nearest-even (no NaN inputs here)
    return (unsigned short)(u >> 16);
}

// ---- LDS offsets (bytes) ----
#define OFF_W1L   0          // [8 kblk][128 n][8] bf16  = 16384
#define OFF_W2L   16384      // [16][128][8] bf16        = 32768
#define OFF_W3L   49152      // [16][16][8] bf16         = 4096
#define OFF_B1    53248      // 128 f32
#define OFF_B2    53760      // 128 f32
#define OFF_B3    54272      // 16 f32 (+pad)
#define OFF_SEL   54336      // 64 f32
#define OFF_XS    54592      // [16 c][3 r][264 q] f32   = 50688
#define OFF_FE    105280     // [64 p][64 k] bf16 (xor-swizzled 16B blocks) = 8192
#define OFF_H1    113472     // [64][128] bf16 swizzled  = 16384
#define OFF_H2    129856     // [64][128] bf16 swizzled  = 16384
#define OFF_U     146240     // [64][17] f32 (pad 16->17 vs bank conflicts) = 4352
#define LDS_TOTAL 150592

extern "C" __global__ __launch_bounds__(TPB, 1)
void nca_fused(const float* __restrict__ x, const float* __restrict__ fmask,
               const float* __restrict__ w1, const float* __restrict__ b1,
               const float* __restrict__ w2, const float* __restrict__ b2,
               const float* __restrict__ w3, const float* __restrict__ b3,
               float* __restrict__ out) {
    extern __shared__ char smem[];
    unsigned short* W1L = (unsigned short*)(smem + OFF_W1L);
    unsigned short* W2L = (unsigned short*)(smem + OFF_W2L);
    unsigned short* W3L = (unsigned short*)(smem + OFF_W3L);
    float* b1s = (float*)(smem + OFF_B1);
    float* b2s = (float*)(smem + OFF_B2);
    float* b3s = (float*)(smem + OFF_B3);
    float* sel = (float*)(smem + OFF_SEL);
    float* xs  = (float*)(smem + OFF_XS);
    char*  FE  = smem + OFF_FE;
    char*  H1  = smem + OFF_H1;
    char*  H2  = smem + OFF_H2;
    float* uB  = (float*)(smem + OFF_U);

    const int t  = threadIdx.x;
    const int bb = blockIdx.x >> 4;   // batch
    const int hs = blockIdx.x & 15;   // row strip

    // ---- stage weights into B-frag layout: elem (k,n) -> [(k>>3)][n][k&7] ----
    for (int idx = t; idx < 64 * 128; idx += TPB) {
        int k = idx >> 7, n = idx & 127;
        float v = (k < 48) ? w1[k * 128 + n] : 0.f;   // K-pad 48 -> 64
        W1L[(k >> 3) * 1024 + n * 8 + (k & 7)] = f2bf(v);
    }
    for (int idx = t; idx < 128 * 128; idx += TPB) {
        int k = idx >> 7, n = idx & 127;
        W2L[(k >> 3) * 1024 + n * 8 + (k & 7)] = f2bf(w2[idx]);
    }
    for (int idx = t; idx < 128 * 16; idx += TPB) {
        int k = idx >> 4, n = idx & 15;
        W3L[(k >> 3) * 128 + n * 8 + (k & 7)] = f2bf(w3[idx]);
    }
    if (t < 128) { b1s[t] = b1[t]; b2s[t] = b2[t]; }
    if (t < 16)  { b3s[t] = b3[t]; }

    const int wave = t >> 6;
    const int lane = t & 63;
    const int quad = lane >> 4;
    const int ln   = lane & 15;

    // K-pad feature blocks kg=6,7: zero once (never rewritten; swizzled slots disjoint)
    if (wave >= 6) {
        int p = lane;
        int kb = wave ^ (p & 7);
        *(int4*)(FE + p * 128 + kb * 16) = make_int4(0, 0, 0, 0);
    }
    __syncthreads();

    for (int hh = 0; hh < 16; ++hh) {
        const int h = hs * 16 + hh;
        __syncthreads();   // xs overwrite vs previous iteration's readers
        // ---- stage fp32 x window: rows h-1..h+1, cols -1..256 (q = w+1 in [0,258)) ----
        for (int idx = t; idx < 16 * 3 * 264; idx += TPB) {
            int c = idx / 792;
            int rem = idx - c * 792;
            int r = rem / 264;
            int q = rem - r * 264;
            float v = 0.f;
            int hr = h - 1 + r;
            int w  = q - 1;
            if (q < 258 && hr >= 0 && hr < 256 && (unsigned)w < 256u)
                v = x[((bb * 16 + c) * 256 + hr) * 256 + w];
            xs[(c * 3 + r) * 264 + q] = v;
        }

        for (int wt = 0; wt < 4; ++wt) {
            const int w0 = wt * 64;
            __syncthreads();   // xs ready; feats/sel overwrite vs prev readers
            // ---- feats (fp32 sobel -> bf16, XOR-swizzled A layout) + sel ----
            {
                const int p = lane;
                const int q = w0 + p + 1;
                if (wave < 2) {          // k = 0..15 : x copy
                    s16x8 tmp;
                    const int c0 = wave * 8;
#pragma unroll
                    for (int j = 0; j < 8; ++j)
                        tmp[j] = (short)f2bf(xs[((c0 + j) * 3 + 1) * 264 + q]);
                    *(s16x8*)(FE + p * 128 + ((wave ^ (p & 7)) * 16)) = tmp;
                } else if (wave < 4) {   // k = 16..31 : sobel_x = s[q+1]-s[q-1], s = r0+2r1+r2
                    s16x8 tmp;
                    const int c0 = (wave - 2) * 8;
#pragma unroll
                    for (int j = 0; j < 8; ++j) {
                        const float* bse = xs + (c0 + j) * 792 + q;
                        float sL = bse[-1] + 2.f * bse[263] + bse[527];
                        float sR = bse[ 1] + 2.f * bse[265] + bse[529];
                        tmp[j] = (short)f2bf(sR - sL);
                    }
                    *(s16x8*)(FE + p * 128 + ((wave ^ (p & 7)) * 16)) = tmp;
                } else if (wave < 6) {   // k = 32..47 : sobel_y = d[q-1]+2d[q]+d[q+1], d = r2-r0
                    s16x8 tmp;
                    const int c0 = (wave - 4) * 8;
#pragma unroll
                    for (int j = 0; j < 8; ++j) {
                        const float* bse = xs + (c0 + j) * 792 + q;
                        float dm = bse[527] - bse[-1];
                        float dc = bse[528] - bse[ 0];
                        float dp = bse[529] - bse[ 1];
                        tmp[j] = (short)f2bf(dm + 2.f * dc + dp);
                    }
                    *(s16x8*)(FE + p * 128 + ((wave ^ (p & 7)) * 16)) = tmp;
                } else if (wave == 7) {  // sel: 3x3 maxpool of alpha (ch 3, exact fp32) x fire
                    const float* a = xs + 3 * 792 + q;
                    float m = a[-1];
                    m = fmaxf(m, a[0]);   m = fmaxf(m, a[1]);
                    m = fmaxf(m, a[263]); m = fmaxf(m, a[264]); m = fmaxf(m, a[265]);
                    m = fmaxf(m, a[527]); m = fmaxf(m, a[528]); m = fmaxf(m, a[529]);
                    float fv = fmask[(bb * 256 + h) * 256 + w0 + p];
                    sel[p] = (fv != 0.f && m > 0.1f) ? 1.f : 0.f;
                }
            }
            __syncthreads();
            // ---- layer 1: H1 = relu(F @ W1 + b1), K=64(padded), each wave 16 rows x 64 cols
            {
                const int rt = wave >> 1, ch = wave & 1;
                const int prow = rt * 16 + ln;
                const int sw = ln & 7;
                bf16x8 a0 = *(const bf16x8*)(FE + prow * 128 + ((0 + quad) ^ sw) * 16);
                bf16x8 a1 = *(const bf16x8*)(FE + prow * 128 + ((4 + quad) ^ sw) * 16);
#pragma unroll
                for (int i = 0; i < 4; ++i) {
                    int n = (ch * 4 + i) * 16 + ln;
                    float bias = b1s[n];
                    f32x4 acc = { bias, bias, bias, bias };
                    bf16x8 bf0 = *(const bf16x8*)((char*)W1L + ((0 + quad) * 1024 + n * 8) * 2);
                    bf16x8 bf1 = *(const bf16x8*)((char*)W1L + ((4 + quad) * 1024 + n * 8) * 2);
                    acc = __builtin_amdgcn_mfma_f32_16x16x32_bf16(a0, bf0, acc, 0, 0, 0);
                    acc = __builtin_amdgcn_mfma_f32_16x16x32_bf16(a1, bf1, acc, 0, 0, 0);
#pragma unroll
                    for (int r = 0; r < 4; ++r) {
                        int pp = rt * 16 + quad * 4 + r;
                        float v = fmaxf(acc[r], 0.f);
                        ((unsigned short*)H1)[pp * 128 + ((n >> 3) ^ (pp & 7)) * 8 + (n & 7)] = f2bf(v);
                    }
                }
            }
            __syncthreads();
            // ---- layer 2: H2 = relu(H1 @ W2 + b2), K=128
            {
                const int rt = wave >> 1, ch = wave & 1;
                const int prow = rt * 16 + ln;
                const int sw = ln & 7;
                bf16x8 A[4];
#pragma unroll
                for (int f = 0; f < 4; ++f)
                    A[f] = *(const bf16x8*)(H1 + prow * 256 + ((f * 4 + quad) ^ sw) * 16);
#pragma unroll
                for (int i = 0; i < 4; ++i) {
                    int n = (ch * 4 + i) * 16 + ln;
                    float bias = b2s[n];
                    f32x4 acc = { bias, bias, bias, bias };
#pragma unroll
                    for (int f = 0; f < 4; ++f) {
                        bf16x8 bfr = *(const bf16x8*)((char*)W2L + ((f * 4 + quad) * 1024 + n * 8) * 2);
                        acc = __builtin_amdgcn_mfma_f32_16x16x32_bf16(A[f], bfr, acc, 0, 0, 0);
                    }
#pragma unroll
                    for (int r = 0; r < 4; ++r) {
                        int pp = rt * 16 + quad * 4 + r;
                        float v = fmaxf(acc[r], 0.f);
                        ((unsigned short*)H2)[pp * 128 + ((n >> 3) ^ (pp & 7)) * 8 + (n & 7)] = f2bf(v);
                    }
                }
            }
            __syncthreads();
            // ---- layer 3: U = H2 @ W3 + b3 (N=16), waves 0..3 only
            if (wave < 4) {
                const int rt = wave;
                const int prow = rt * 16 + ln;
                const int sw = ln & 7;
                f32x4 acc = { b3s[ln], b3s[ln], b3s[ln], b3s[ln] };
#pragma unroll
                for (int f = 0; f < 4; ++f) {
                    bf16x8 a = *(const bf16x8*)(H2 + prow * 256 + ((f * 4 + quad) ^ sw) * 16);
                    bf16x8 bfr = *(const bf16x8*)((char*)W3L + ((f * 4 + quad) * 128 + ln * 8) * 2);
                    acc = __builtin_amdgcn_mfma_f32_16x16x32_bf16(a, bfr, acc, 0, 0, 0);
                }
#pragma unroll
                for (int r = 0; r < 4; ++r) {
                    int pp = rt * 16 + quad * 4 + r;
                    uB[pp * 17 + ln] = acc[r];
                }
            }
            __syncthreads();
            // ---- epilogue: mask + coalesced float2 store (NCHW) ----
            {
                const int p2 = (t & 31) * 2;
                const int c  = t >> 5;
                float v0 = uB[p2 * 17 + c] * sel[p2];
                float v1 = uB[(p2 + 1) * 17 + c] * sel[p2 + 1];
                float2 vv = make_float2(v0, v1);
                *(float2*)&out[((bb * 16 + c) * 256 + h) * 256 + w0 + p2] = vv;
            }
        }
    }
}

extern "C" void kernel_launch(void* const* d_in, const int* in_sizes, int n_in,
                              void* d_out, int out_size, void* d_ws, size_t ws_size,
                              hipStream_t stream) {
    const float* x  = (const float*)d_in[0];
    const float* fm = (const float*)d_in[1];
    const float* w1 = (const float*)d_in[2];
    const float* b1 = (const float*)d_in[3];
    const float* w2 = (const float*)d_in[4];
    const float* b2 = (const float*)d_in[5];
    const float* w3 = (const float*)d_in[6];
    const float* b3 = (const float*)d_in[7];
    float* o = (float*)d_out;

    hipFuncSetAttribute((const void*)nca_fused,
                        hipFuncAttributeMaxDynamicSharedMemorySize, LDS_TOTAL);
    nca_fused<<<dim3(256), dim3(TPB), LDS_TOTAL, stream>>>(x, fm, w1, b1, w2, b2, w3, b3, o);
}